// Round 1
// baseline (293.193 us; speedup 1.0000x reference)
//
#include <hip/hip_runtime.h>

#define HW 4096
#define CCH 128
#define NB 4

typedef short bf16x8 __attribute__((ext_vector_type(8)));
typedef float f32x4 __attribute__((ext_vector_type(4)));

__device__ __forceinline__ unsigned short f2bf(float f){
  union { float fv; unsigned u; } v; v.fv = f;
  unsigned r = v.u + 0x7fffu + ((v.u >> 16) & 1u);
  return (unsigned short)(r >> 16);
}

__device__ __forceinline__ f32x4 mfma16(bf16x8 a, bf16x8 b, f32x4 c){
  return __builtin_amdgcn_mfma_f32_16x16x32_bf16(a, b, c, 0, 0, 0);
}

// ---------- Kernel A: group-norm stats (mean, rstd per (n,g)) ----------
__global__ __launch_bounds__(256) void gn_stats_k(const float* __restrict__ x,
                                                  float* __restrict__ stats){
  int gid = blockIdx.x;  // n*32 + g, groups are 16384 contiguous floats
  const float4* p = (const float4*)(x + (size_t)gid * 16384);
  float s = 0.f, q = 0.f;
  #pragma unroll
  for (int i = 0; i < 16; i++){
    float4 v = p[threadIdx.x + 256 * i];
    s += v.x + v.y + v.z + v.w;
    q += v.x * v.x + v.y * v.y + v.z * v.z + v.w * v.w;
  }
  #pragma unroll
  for (int d = 1; d < 64; d <<= 1){ s += __shfl_xor(s, d); q += __shfl_xor(q, d); }
  __shared__ float red[8];
  int w = threadIdx.x >> 6;
  if ((threadIdx.x & 63) == 0){ red[2 * w] = s; red[2 * w + 1] = q; }
  __syncthreads();
  if (threadIdx.x == 0){
    float S = red[0] + red[2] + red[4] + red[6];
    float Q = red[1] + red[3] + red[5] + red[7];
    float mean = S * (1.f / 16384.f);
    float var  = Q * (1.f / 16384.f) - mean * mean;
    stats[2 * gid]     = mean;
    stats[2 * gid + 1] = rsqrtf(var + 1e-5f);
  }
}

// ---------- Kernel B: apply GN + transpose NCHW -> [N, L, C] bf16 ----------
__global__ __launch_bounds__(256) void gn_apply_k(const float* __restrict__ x,
    const float* __restrict__ stats, const float* __restrict__ sc,
    const float* __restrict__ bi, unsigned short* __restrict__ ht){
  int n = blockIdx.y, l0 = blockIdx.x * 64, tid = threadIdx.x;
  __shared__ __align__(16) unsigned short hs[64][136];
  #pragma unroll
  for (int i = 0; i < 32; i++){
    int c = (tid >> 6) + 4 * i;   // wave-uniform channel
    int l = tid & 63;             // coalesced over l
    float v = x[((size_t)(n * CCH + c)) * HW + l0 + l];
    int grp = n * 32 + (c >> 2);
    float r = (v - stats[2 * grp]) * stats[2 * grp + 1] * sc[c] + bi[c];
    hs[l][c] = f2bf(r);
  }
  __syncthreads();
  #pragma unroll
  for (int i = 0; i < 4; i++){
    int ch = tid + 256 * i;
    int l = ch >> 4, cb = (ch & 15) * 8;
    *(uint4*)&ht[((size_t)(n * HW) + l0 + l) * CCH + cb] = *(const uint4*)&hs[l][cb];
  }
}

// ---------- Kernel C: fused QKV projection ----------
// Q,K -> [N, L, C] bf16 (Q pre-scaled by C^-0.5); V -> transposed [N, C, L] bf16
__global__ __launch_bounds__(256) void qkv_k(const unsigned short* __restrict__ ht,
    const float* __restrict__ wq, const float* __restrict__ bq,
    const float* __restrict__ wk, const float* __restrict__ bk,
    const float* __restrict__ wv, const float* __restrict__ bv,
    unsigned short* __restrict__ Qg, unsigned short* __restrict__ Kg,
    unsigned short* __restrict__ Vt){
  int n = blockIdx.y, l0 = blockIdx.x * 64, tid = threadIdx.x;
  int w = tid >> 6, lane = tid & 63, l15 = lane & 15, g = lane >> 4;
  __shared__ __align__(16) unsigned short hs[64][136];
  __shared__ __align__(16) unsigned short wm[128][136];
  {
    int row = tid >> 2, cq = (tid & 3) * 32;
    #pragma unroll
    for (int i = 0; i < 4; i++)
      *(uint4*)&hs[row][cq + 8 * i] =
          *(const uint4*)&ht[((size_t)(n * HW) + l0 + row) * CCH + cq + 8 * i];
  }
  const float* Wm[3] = {wq, wk, wv};
  const float* Bm[3] = {bq, bk, bv};
  #pragma unroll
  for (int m = 0; m < 3; m++){
    __syncthreads();
    #pragma unroll
    for (int i = 0; i < 16; i++){
      int ch = tid + 256 * i;
      int row = ch >> 5, c = (ch & 31) * 4;
      float4 v = *(const float4*)&Wm[m][row * CCH + c];
      ushort4 b; b.x = f2bf(v.x); b.y = f2bf(v.y); b.z = f2bf(v.z); b.w = f2bf(v.w);
      *(ushort4*)&wm[row][c] = b;
    }
    __syncthreads();
    bf16x8 a[4];
    #pragma unroll
    for (int kc = 0; kc < 4; kc++)
      a[kc] = *reinterpret_cast<const bf16x8*>(&hs[16 * w + l15][32 * kc + 8 * g]);
    f32x4 acc[8];
    #pragma unroll
    for (int ct = 0; ct < 8; ct++) acc[ct] = (f32x4)(0.f);
    #pragma unroll
    for (int ct = 0; ct < 8; ct++)
      #pragma unroll
      for (int kc = 0; kc < 4; kc++)
        acc[ct] = mfma16(a[kc],
            *reinterpret_cast<const bf16x8*>(&wm[16 * ct + l15][32 * kc + 8 * g]),
            acc[ct]);
    if (m < 2){
      float qs = (m == 0) ? 0.08838834764831845f : 1.0f;  // 128^-0.5 folded into Q
      unsigned short* dst = (m == 0) ? Qg : Kg;
      #pragma unroll
      for (int ct = 0; ct < 8; ct++){
        int o = 16 * ct + l15;
        float bias = Bm[m][o];
        #pragma unroll
        for (int r = 0; r < 4; r++){
          int l = l0 + 16 * w + 4 * g + r;
          dst[((size_t)(n * HW) + l) * CCH + o] = f2bf((acc[ct][r] + bias) * qs);
        }
      }
    } else {
      #pragma unroll
      for (int ct = 0; ct < 8; ct++){
        int o = 16 * ct + l15;
        float bias = Bm[2][o];
        ushort4 pk;
        pk.x = f2bf(acc[ct][0] + bias); pk.y = f2bf(acc[ct][1] + bias);
        pk.z = f2bf(acc[ct][2] + bias); pk.w = f2bf(acc[ct][3] + bias);
        *(ushort4*)&Vt[((size_t)(n * CCH) + o) * HW + l0 + 16 * w + 4 * g] = pk;
      }
    }
  }
}

// ---------- Kernel D: flash attention ----------
// grid (64 q-tiles, 4 batches), 4 waves/block, each wave owns 16 q-rows.
__global__ __launch_bounds__(256) void attn_k(const unsigned short* __restrict__ Qg,
    const unsigned short* __restrict__ Kg, const unsigned short* __restrict__ Vt,
    unsigned short* __restrict__ Og){
  int n = blockIdx.y, q0 = blockIdx.x * 64, tid = threadIdx.x;
  int w = tid >> 6, lane = tid & 63, l15 = lane & 15, g = lane >> 4;
  __shared__ __align__(16) unsigned short Ks[64][136];   // [kv][c], +8 pad: 2-way banks
  __shared__ __align__(16) unsigned short Vs[128][72];   // [c][kv], +8 pad
  __shared__ __align__(16) unsigned short Ps[4][16][72]; // per-wave P, +8 pad
  bf16x8 qf[4];
  #pragma unroll
  for (int kc = 0; kc < 4; kc++)
    qf[kc] = *reinterpret_cast<const bf16x8*>(
        &Qg[((size_t)(n * HW) + q0 + 16 * w + l15) * CCH + 32 * kc + 8 * g]);
  f32x4 ov[8];
  #pragma unroll
  for (int i = 0; i < 8; i++) ov[i] = (f32x4)(0.f);
  float mrun[4] = {-3.0e38f, -3.0e38f, -3.0e38f, -3.0e38f};
  float lrun[4] = {0.f, 0.f, 0.f, 0.f};

  for (int kv0 = 0; kv0 < HW; kv0 += 64){
    __syncthreads();
    {
      int row = tid >> 2, cq = (tid & 3) * 32;
      #pragma unroll
      for (int i = 0; i < 4; i++)
        *(uint4*)&Ks[row][cq + 8 * i] =
            *(const uint4*)&Kg[((size_t)(n * HW) + kv0 + row) * CCH + cq + 8 * i];
      int o = tid >> 1, hh = (tid & 1) * 32;
      #pragma unroll
      for (int i = 0; i < 4; i++)
        *(uint4*)&Vs[o][hh + 8 * i] =
            *(const uint4*)&Vt[((size_t)(n * CCH) + o) * HW + kv0 + hh + 8 * i];
    }
    __syncthreads();
    // S = Q K^T  (Q pre-scaled)
    f32x4 s[4];
    #pragma unroll
    for (int ct = 0; ct < 4; ct++){
      f32x4 acc = (f32x4)(0.f);
      #pragma unroll
      for (int kc = 0; kc < 4; kc++)
        acc = mfma16(qf[kc],
            *reinterpret_cast<const bf16x8*>(&Ks[16 * ct + l15][32 * kc + 8 * g]), acc);
      s[ct] = acc;
    }
    // online softmax; row r of lane = q-row (4g + r); cols spread over 16-lane group
    float mx[4];
    #pragma unroll
    for (int r = 0; r < 4; r++)
      mx[r] = fmaxf(fmaxf(s[0][r], s[1][r]), fmaxf(s[2][r], s[3][r]));
    #pragma unroll
    for (int d = 1; d < 16; d <<= 1)
      #pragma unroll
      for (int r = 0; r < 4; r++) mx[r] = fmaxf(mx[r], __shfl_xor(mx[r], d));
    float al[4];
    #pragma unroll
    for (int r = 0; r < 4; r++){
      float mn = fmaxf(mrun[r], mx[r]);
      al[r] = __expf(mrun[r] - mn);
      mrun[r] = mn;
    }
    #pragma unroll
    for (int ct = 0; ct < 4; ct++)
      #pragma unroll
      for (int r = 0; r < 4; r++) s[ct][r] = __expf(s[ct][r] - mrun[r]);
    float rs[4];
    #pragma unroll
    for (int r = 0; r < 4; r++) rs[r] = s[0][r] + s[1][r] + s[2][r] + s[3][r];
    #pragma unroll
    for (int d = 1; d < 16; d <<= 1)
      #pragma unroll
      for (int r = 0; r < 4; r++) rs[r] += __shfl_xor(rs[r], d);
    #pragma unroll
    for (int r = 0; r < 4; r++) lrun[r] = lrun[r] * al[r] + rs[r];
    #pragma unroll
    for (int ct = 0; ct < 8; ct++)
      #pragma unroll
      for (int r = 0; r < 4; r++) ov[ct][r] *= al[r];
    // P -> per-wave LDS (re-fragment for PV A-operand)
    #pragma unroll
    for (int ct = 0; ct < 4; ct++)
      #pragma unroll
      for (int r = 0; r < 4; r++)
        Ps[w][4 * g + r][16 * ct + l15] = f2bf(s[ct][r]);
    // O += P V
    #pragma unroll
    for (int ct = 0; ct < 8; ct++){
      #pragma unroll
      for (int kc = 0; kc < 2; kc++){
        bf16x8 pa = *reinterpret_cast<const bf16x8*>(&Ps[w][l15][32 * kc + 8 * g]);
        bf16x8 vb = *reinterpret_cast<const bf16x8*>(&Vs[16 * ct + l15][32 * kc + 8 * g]);
        ov[ct] = mfma16(pa, vb, ov[ct]);
      }
    }
  }
  #pragma unroll
  for (int r = 0; r < 4; r++) lrun[r] = 1.f / lrun[r];
  #pragma unroll
  for (int ct = 0; ct < 8; ct++){
    int o = 16 * ct + l15;
    #pragma unroll
    for (int r = 0; r < 4; r++){
      int l = q0 + 16 * w + 4 * g + r;
      Og[((size_t)(n * HW) + l) * CCH + o] = f2bf(ov[ct][r] * lrun[r]);
    }
  }
}

// ---------- Kernel E: output projection + bias + residual ----------
__global__ __launch_bounds__(256) void projout_k(const unsigned short* __restrict__ Og,
    const float* __restrict__ wp, const float* __restrict__ bp,
    const float* __restrict__ x, float* __restrict__ out){
  int n = blockIdx.y, l0 = blockIdx.x * 64, tid = threadIdx.x;
  int w = tid >> 6, lane = tid & 63, l15 = lane & 15, g = lane >> 4;
  __shared__ __align__(16) unsigned short hs[64][136];
  __shared__ __align__(16) unsigned short wm[128][136];
  {
    int row = tid >> 2, cq = (tid & 3) * 32;
    #pragma unroll
    for (int i = 0; i < 4; i++)
      *(uint4*)&hs[row][cq + 8 * i] =
          *(const uint4*)&Og[((size_t)(n * HW) + l0 + row) * CCH + cq + 8 * i];
  }
  #pragma unroll
  for (int i = 0; i < 16; i++){
    int ch = tid + 256 * i;
    int row = ch >> 5, c = (ch & 31) * 4;
    float4 v = *(const float4*)&wp[row * CCH + c];
    ushort4 b; b.x = f2bf(v.x); b.y = f2bf(v.y); b.z = f2bf(v.z); b.w = f2bf(v.w);
    *(ushort4*)&wm[row][c] = b;
  }
  __syncthreads();
  bf16x8 a[4];
  #pragma unroll
  for (int kc = 0; kc < 4; kc++)
    a[kc] = *reinterpret_cast<const bf16x8*>(&hs[16 * w + l15][32 * kc + 8 * g]);
  f32x4 acc[8];
  #pragma unroll
  for (int ct = 0; ct < 8; ct++) acc[ct] = (f32x4)(0.f);
  #pragma unroll
  for (int ct = 0; ct < 8; ct++)
    #pragma unroll
    for (int kc = 0; kc < 4; kc++)
      acc[ct] = mfma16(a[kc],
          *reinterpret_cast<const bf16x8*>(&wm[16 * ct + l15][32 * kc + 8 * g]),
          acc[ct]);
  #pragma unroll
  for (int ct = 0; ct < 8; ct++){
    int o = 16 * ct + l15;
    float bias = bp[o];
    size_t base = ((size_t)(n * CCH) + o) * HW + l0 + 16 * w + 4 * g;
    float4 xr = *(const float4*)&x[base];
    float4 res;
    res.x = xr.x + acc[ct][0] + bias;
    res.y = xr.y + acc[ct][1] + bias;
    res.z = xr.z + acc[ct][2] + bias;
    res.w = xr.w + acc[ct][3] + bias;
    *(float4*)&out[base] = res;
  }
}

extern "C" void kernel_launch(void* const* d_in, const int* in_sizes, int n_in,
                              void* d_out, int out_size, void* d_ws, size_t ws_size,
                              hipStream_t stream){
  const float* x    = (const float*)d_in[0];
  const float* gnsc = (const float*)d_in[1];
  const float* gnb  = (const float*)d_in[2];
  const float* wq   = (const float*)d_in[3];
  const float* bq   = (const float*)d_in[4];
  const float* wk   = (const float*)d_in[5];
  const float* bk   = (const float*)d_in[6];
  const float* wv   = (const float*)d_in[7];
  const float* bv   = (const float*)d_in[8];
  const float* wp   = (const float*)d_in[9];
  const float* bp   = (const float*)d_in[10];
  float* out = (float*)d_out;

  char* ws = (char*)d_ws;
  const size_t BUF = (size_t)NB * HW * CCH * sizeof(unsigned short);  // 4 MiB
  float* stats       = (float*)ws;
  unsigned short* ht = (unsigned short*)(ws + 4096);
  unsigned short* Qg = (unsigned short*)(ws + 4096 + BUF);
  unsigned short* Kg = (unsigned short*)(ws + 4096 + 2 * BUF);
  unsigned short* Vt = (unsigned short*)(ws + 4096 + 3 * BUF);
  unsigned short* Og = ht;  // ht dead after qkv_k; alias for attention output

  gn_stats_k<<<128, 256, 0, stream>>>(x, stats);
  gn_apply_k<<<dim3(64, NB), 256, 0, stream>>>(x, stats, gnsc, gnb, ht);
  qkv_k<<<dim3(64, NB), 256, 0, stream>>>(ht, wq, bq, wk, bk, wv, bv, Qg, Kg, Vt);
  attn_k<<<dim3(64, NB), 256, 0, stream>>>(Qg, Kg, Vt, Og);
  projout_k<<<dim3(64, NB), 256, 0, stream>>>(Og, wp, bp, x, out);
}

// Round 2
// 275.474 us; speedup vs baseline: 1.0643x; 1.0643x over previous
//
#include <hip/hip_runtime.h>

#define HW 4096
#define CCH 128
#define NB 4
#define SPLITS 2
#define KVS (HW / SPLITS)   // 2048 keys per split
#define NT (KVS / 64)       // 32 KV tiles per split

typedef short bf16x8 __attribute__((ext_vector_type(8)));
typedef float f32x4 __attribute__((ext_vector_type(4)));

__device__ __forceinline__ unsigned short f2bf(float f){
  union { float fv; unsigned u; } v; v.fv = f;
  unsigned r = v.u + 0x7fffu + ((v.u >> 16) & 1u);
  return (unsigned short)(r >> 16);
}
__device__ __forceinline__ float bf2f(unsigned short u){
  return __uint_as_float(((unsigned)u) << 16);
}

__device__ __forceinline__ f32x4 mfma16(bf16x8 a, bf16x8 b, f32x4 c){
  return __builtin_amdgcn_mfma_f32_16x16x32_bf16(a, b, c, 0, 0, 0);
}

// ---------- Kernel A: group-norm stats (mean, rstd per (n,g)) ----------
__global__ __launch_bounds__(256) void gn_stats_k(const float* __restrict__ x,
                                                  float* __restrict__ stats){
  int gid = blockIdx.x;  // n*32 + g, groups are 16384 contiguous floats
  const float4* p = (const float4*)(x + (size_t)gid * 16384);
  float s = 0.f, q = 0.f;
  #pragma unroll
  for (int i = 0; i < 16; i++){
    float4 v = p[threadIdx.x + 256 * i];
    s += v.x + v.y + v.z + v.w;
    q += v.x * v.x + v.y * v.y + v.z * v.z + v.w * v.w;
  }
  #pragma unroll
  for (int d = 1; d < 64; d <<= 1){ s += __shfl_xor(s, d); q += __shfl_xor(q, d); }
  __shared__ float red[8];
  int w = threadIdx.x >> 6;
  if ((threadIdx.x & 63) == 0){ red[2 * w] = s; red[2 * w + 1] = q; }
  __syncthreads();
  if (threadIdx.x == 0){
    float S = red[0] + red[2] + red[4] + red[6];
    float Q = red[1] + red[3] + red[5] + red[7];
    float mean = S * (1.f / 16384.f);
    float var  = Q * (1.f / 16384.f) - mean * mean;
    stats[2 * gid]     = mean;
    stats[2 * gid + 1] = rsqrtf(var + 1e-5f);
  }
}

// ---------- Kernel B: apply GN + transpose NCHW -> [N, L, C] bf16 ----------
__global__ __launch_bounds__(256) void gn_apply_k(const float* __restrict__ x,
    const float* __restrict__ stats, const float* __restrict__ sc,
    const float* __restrict__ bi, unsigned short* __restrict__ ht){
  int n = blockIdx.y, l0 = blockIdx.x * 64, tid = threadIdx.x;
  __shared__ __align__(16) unsigned short hs[64][136];
  #pragma unroll
  for (int i = 0; i < 32; i++){
    int c = (tid >> 6) + 4 * i;   // wave-uniform channel
    int l = tid & 63;             // coalesced over l
    float v = x[((size_t)(n * CCH + c)) * HW + l0 + l];
    int grp = n * 32 + (c >> 2);
    float r = (v - stats[2 * grp]) * stats[2 * grp + 1] * sc[c] + bi[c];
    hs[l][c] = f2bf(r);
  }
  __syncthreads();
  #pragma unroll
  for (int i = 0; i < 4; i++){
    int ch = tid + 256 * i;
    int l = ch >> 4, cb = (ch & 15) * 8;
    *(uint4*)&ht[((size_t)(n * HW) + l0 + l) * CCH + cb] = *(const uint4*)&hs[l][cb];
  }
}

// ---------- Kernel C: fused QKV projection ----------
// Q,K -> [N, L, C] bf16 (Q pre-scaled by C^-0.5); V -> transposed [N, C, L] bf16
__global__ __launch_bounds__(256) void qkv_k(const unsigned short* __restrict__ ht,
    const float* __restrict__ wq, const float* __restrict__ bq,
    const float* __restrict__ wk, const float* __restrict__ bk,
    const float* __restrict__ wv, const float* __restrict__ bv,
    unsigned short* __restrict__ Qg, unsigned short* __restrict__ Kg,
    unsigned short* __restrict__ Vt){
  int n = blockIdx.y, l0 = blockIdx.x * 64, tid = threadIdx.x;
  int w = tid >> 6, lane = tid & 63, l15 = lane & 15, g = lane >> 4;
  __shared__ __align__(16) unsigned short hs[64][136];
  __shared__ __align__(16) unsigned short wm[128][136];
  {
    int row = tid >> 2, cq = (tid & 3) * 32;
    #pragma unroll
    for (int i = 0; i < 4; i++)
      *(uint4*)&hs[row][cq + 8 * i] =
          *(const uint4*)&ht[((size_t)(n * HW) + l0 + row) * CCH + cq + 8 * i];
  }
  const float* Wm[3] = {wq, wk, wv};
  const float* Bm[3] = {bq, bk, bv};
  #pragma unroll
  for (int m = 0; m < 3; m++){
    __syncthreads();
    #pragma unroll
    for (int i = 0; i < 16; i++){
      int ch = tid + 256 * i;
      int row = ch >> 5, c = (ch & 31) * 4;
      float4 v = *(const float4*)&Wm[m][row * CCH + c];
      ushort4 b; b.x = f2bf(v.x); b.y = f2bf(v.y); b.z = f2bf(v.z); b.w = f2bf(v.w);
      *(ushort4*)&wm[row][c] = b;
    }
    __syncthreads();
    bf16x8 a[4];
    #pragma unroll
    for (int kc = 0; kc < 4; kc++)
      a[kc] = *reinterpret_cast<const bf16x8*>(&hs[16 * w + l15][32 * kc + 8 * g]);
    f32x4 acc[8];
    #pragma unroll
    for (int ct = 0; ct < 8; ct++) acc[ct] = (f32x4)(0.f);
    #pragma unroll
    for (int ct = 0; ct < 8; ct++)
      #pragma unroll
      for (int kc = 0; kc < 4; kc++)
        acc[ct] = mfma16(a[kc],
            *reinterpret_cast<const bf16x8*>(&wm[16 * ct + l15][32 * kc + 8 * g]),
            acc[ct]);
    if (m < 2){
      float qs = (m == 0) ? 0.08838834764831845f : 1.0f;  // 128^-0.5 folded into Q
      unsigned short* dst = (m == 0) ? Qg : Kg;
      #pragma unroll
      for (int ct = 0; ct < 8; ct++){
        int o = 16 * ct + l15;
        float bias = Bm[m][o];
        #pragma unroll
        for (int r = 0; r < 4; r++){
          int l = l0 + 16 * w + 4 * g + r;
          dst[((size_t)(n * HW) + l) * CCH + o] = f2bf((acc[ct][r] + bias) * qs);
        }
      }
    } else {
      #pragma unroll
      for (int ct = 0; ct < 8; ct++){
        int o = 16 * ct + l15;
        float bias = Bm[2][o];
        ushort4 pk;
        pk.x = f2bf(acc[ct][0] + bias); pk.y = f2bf(acc[ct][1] + bias);
        pk.z = f2bf(acc[ct][2] + bias); pk.w = f2bf(acc[ct][3] + bias);
        *(ushort4*)&Vt[((size_t)(n * CCH) + o) * HW + l0 + 16 * w + 4 * g] = pk;
      }
    }
  }
}

// ---------- Kernel D: flash attention with KV-split ----------
// grid (64 q-tiles, NB batches, SPLITS), 4 waves/block, wave owns 16 q-rows.
// Writes UNNORMALIZED O~ (bf16) per split + (m, l) f32 per row.
__global__ __launch_bounds__(256) void attn_k(const unsigned short* __restrict__ Qg,
    const unsigned short* __restrict__ Kg, const unsigned short* __restrict__ Vt,
    unsigned short* __restrict__ Op, float* __restrict__ Ml){
  int n = blockIdx.y, q0 = blockIdx.x * 64, sp = blockIdx.z, tid = threadIdx.x;
  int w = tid >> 6, lane = tid & 63, l15 = lane & 15, g = lane >> 4;
  __shared__ __align__(16) unsigned short Ks[64][136];   // [kv][c], +8 pad
  __shared__ __align__(16) unsigned short Vs[128][72];   // [c][kv], +8 pad
  __shared__ __align__(16) unsigned short Ps[4][16][72]; // per-wave P, +8 pad
  bf16x8 qf[4];
  #pragma unroll
  for (int kc = 0; kc < 4; kc++)
    qf[kc] = *reinterpret_cast<const bf16x8*>(
        &Qg[((size_t)(n * HW) + q0 + 16 * w + l15) * CCH + 32 * kc + 8 * g]);
  f32x4 ov[8];
  #pragma unroll
  for (int i = 0; i < 8; i++) ov[i] = (f32x4)(0.f);
  float mrun[4] = {-3.0e38f, -3.0e38f, -3.0e38f, -3.0e38f};
  float lrun[4] = {0.f, 0.f, 0.f, 0.f};

  // register staging (T14): tile t in regs while tile t-1 computes
  int krow = tid >> 2, kcq = (tid & 3) * 32;   // K: row 0..63, 4x16B per thread
  int vrow = tid >> 1, vh = (tid & 1) * 32;    // V: row 0..127, 4x16B per thread
  const size_t kb = (size_t)(n * HW) * CCH;
  const size_t vb = (size_t)(n * CCH) * HW;
  uint4 kn[4], vn[4];
  {
    int kv0 = sp * KVS;
    #pragma unroll
    for (int i = 0; i < 4; i++)
      kn[i] = *(const uint4*)&Kg[kb + (size_t)(kv0 + krow) * CCH + kcq + 8 * i];
    #pragma unroll
    for (int i = 0; i < 4; i++)
      vn[i] = *(const uint4*)&Vt[vb + (size_t)vrow * HW + kv0 + vh + 8 * i];
  }

  for (int t = 0; t < NT; t++){
    __syncthreads();   // LDS consumed by previous iteration
    #pragma unroll
    for (int i = 0; i < 4; i++) *(uint4*)&Ks[krow][kcq + 8 * i] = kn[i];
    #pragma unroll
    for (int i = 0; i < 4; i++) *(uint4*)&Vs[vrow][vh + 8 * i] = vn[i];
    __syncthreads();
    if (t + 1 < NT){   // issue next tile's loads; latency hides under compute
      int kv = sp * KVS + (t + 1) * 64;
      #pragma unroll
      for (int i = 0; i < 4; i++)
        kn[i] = *(const uint4*)&Kg[kb + (size_t)(kv + krow) * CCH + kcq + 8 * i];
      #pragma unroll
      for (int i = 0; i < 4; i++)
        vn[i] = *(const uint4*)&Vt[vb + (size_t)vrow * HW + kv + vh + 8 * i];
    }
    // S = Q K^T  (Q pre-scaled)
    f32x4 s[4];
    #pragma unroll
    for (int ct = 0; ct < 4; ct++){
      f32x4 acc = (f32x4)(0.f);
      #pragma unroll
      for (int kc = 0; kc < 4; kc++)
        acc = mfma16(qf[kc],
            *reinterpret_cast<const bf16x8*>(&Ks[16 * ct + l15][32 * kc + 8 * g]), acc);
      s[ct] = acc;
    }
    // online softmax
    float mx[4];
    #pragma unroll
    for (int r = 0; r < 4; r++)
      mx[r] = fmaxf(fmaxf(s[0][r], s[1][r]), fmaxf(s[2][r], s[3][r]));
    #pragma unroll
    for (int d = 1; d < 16; d <<= 1)
      #pragma unroll
      for (int r = 0; r < 4; r++) mx[r] = fmaxf(mx[r], __shfl_xor(mx[r], d));
    float al[4];
    #pragma unroll
    for (int r = 0; r < 4; r++){
      float mn = fmaxf(mrun[r], mx[r]);
      al[r] = __expf(mrun[r] - mn);
      mrun[r] = mn;
    }
    #pragma unroll
    for (int ct = 0; ct < 4; ct++)
      #pragma unroll
      for (int r = 0; r < 4; r++) s[ct][r] = __expf(s[ct][r] - mrun[r]);
    float rs[4];
    #pragma unroll
    for (int r = 0; r < 4; r++) rs[r] = s[0][r] + s[1][r] + s[2][r] + s[3][r];
    #pragma unroll
    for (int d = 1; d < 16; d <<= 1)
      #pragma unroll
      for (int r = 0; r < 4; r++) rs[r] += __shfl_xor(rs[r], d);
    #pragma unroll
    for (int r = 0; r < 4; r++) lrun[r] = lrun[r] * al[r] + rs[r];
    #pragma unroll
    for (int ct = 0; ct < 8; ct++)
      #pragma unroll
      for (int r = 0; r < 4; r++) ov[ct][r] *= al[r];
    // P -> per-wave LDS (re-fragment for PV A-operand)
    #pragma unroll
    for (int ct = 0; ct < 4; ct++)
      #pragma unroll
      for (int r = 0; r < 4; r++)
        Ps[w][4 * g + r][16 * ct + l15] = f2bf(s[ct][r]);
    // O~ += P V
    #pragma unroll
    for (int ct = 0; ct < 8; ct++){
      #pragma unroll
      for (int kc = 0; kc < 2; kc++){
        bf16x8 pa = *reinterpret_cast<const bf16x8*>(&Ps[w][l15][32 * kc + 8 * g]);
        bf16x8 vb2 = *reinterpret_cast<const bf16x8*>(&Vs[16 * ct + l15][32 * kc + 8 * g]);
        ov[ct] = mfma16(pa, vb2, ov[ct]);
      }
    }
  }
  // epilogue: unnormalized O~ + (m, l)
  size_t obase = (size_t)((sp * NB + n) * HW);
  #pragma unroll
  for (int ct = 0; ct < 8; ct++){
    int o = 16 * ct + l15;
    #pragma unroll
    for (int r = 0; r < 4; r++){
      int l = q0 + 16 * w + 4 * g + r;
      Op[(obase + l) * CCH + o] = f2bf(ov[ct][r]);
    }
  }
  if (l15 == 0){
    #pragma unroll
    for (int r = 0; r < 4; r++){
      int l = q0 + 16 * w + 4 * g + r;
      Ml[(obase + l) * 2]     = mrun[r];
      Ml[(obase + l) * 2 + 1] = lrun[r];
    }
  }
}

// ---------- Kernel D2: combine the KV splits ----------
__global__ __launch_bounds__(256) void comb_k(const unsigned short* __restrict__ Op,
    const float* __restrict__ Ml, unsigned short* __restrict__ Og){
  int idx = blockIdx.x * 256 + threadIdx.x;   // 16384 rows x 16 chunks
  int row = idx >> 4, cb = (idx & 15) * 8;
  const size_t SSTR = (size_t)NB * HW;
  float m0 = Ml[(size_t)row * 2], l0 = Ml[(size_t)row * 2 + 1];
  float m1 = Ml[(SSTR + row) * 2], l1 = Ml[(SSTR + row) * 2 + 1];
  float m = fmaxf(m0, m1);
  float w0 = __expf(m0 - m), w1 = __expf(m1 - m);
  float inv = 1.f / (w0 * l0 + w1 * l1);
  w0 *= inv; w1 *= inv;
  uint4 a = *(const uint4*)&Op[(size_t)row * CCH + cb];
  uint4 b = *(const uint4*)&Op[(SSTR + row) * CCH + cb];
  const unsigned short* au = (const unsigned short*)&a;
  const unsigned short* bu = (const unsigned short*)&b;
  ushort4 lo, hi;
  unsigned short r8[8];
  #pragma unroll
  for (int j = 0; j < 8; j++)
    r8[j] = f2bf(w0 * bf2f(au[j]) + w1 * bf2f(bu[j]));
  lo.x = r8[0]; lo.y = r8[1]; lo.z = r8[2]; lo.w = r8[3];
  hi.x = r8[4]; hi.y = r8[5]; hi.z = r8[6]; hi.w = r8[7];
  *(ushort4*)&Og[(size_t)row * CCH + cb] = lo;
  *(ushort4*)&Og[(size_t)row * CCH + cb + 4] = hi;
}

// ---------- Kernel E: output projection + bias + residual ----------
__global__ __launch_bounds__(256) void projout_k(const unsigned short* __restrict__ Og,
    const float* __restrict__ wp, const float* __restrict__ bp,
    const float* __restrict__ x, float* __restrict__ out){
  int n = blockIdx.y, l0 = blockIdx.x * 64, tid = threadIdx.x;
  int w = tid >> 6, lane = tid & 63, l15 = lane & 15, g = lane >> 4;
  __shared__ __align__(16) unsigned short hs[64][136];
  __shared__ __align__(16) unsigned short wm[128][136];
  {
    int row = tid >> 2, cq = (tid & 3) * 32;
    #pragma unroll
    for (int i = 0; i < 4; i++)
      *(uint4*)&hs[row][cq + 8 * i] =
          *(const uint4*)&Og[((size_t)(n * HW) + l0 + row) * CCH + cq + 8 * i];
  }
  #pragma unroll
  for (int i = 0; i < 16; i++){
    int ch = tid + 256 * i;
    int row = ch >> 5, c = (ch & 31) * 4;
    float4 v = *(const float4*)&wp[row * CCH + c];
    ushort4 b; b.x = f2bf(v.x); b.y = f2bf(v.y); b.z = f2bf(v.z); b.w = f2bf(v.w);
    *(ushort4*)&wm[row][c] = b;
  }
  __syncthreads();
  bf16x8 a[4];
  #pragma unroll
  for (int kc = 0; kc < 4; kc++)
    a[kc] = *reinterpret_cast<const bf16x8*>(&hs[16 * w + l15][32 * kc + 8 * g]);
  f32x4 acc[8];
  #pragma unroll
  for (int ct = 0; ct < 8; ct++) acc[ct] = (f32x4)(0.f);
  #pragma unroll
  for (int ct = 0; ct < 8; ct++)
    #pragma unroll
    for (int kc = 0; kc < 4; kc++)
      acc[ct] = mfma16(a[kc],
          *reinterpret_cast<const bf16x8*>(&wm[16 * ct + l15][32 * kc + 8 * g]),
          acc[ct]);
  #pragma unroll
  for (int ct = 0; ct < 8; ct++){
    int o = 16 * ct + l15;
    float bias = bp[o];
    size_t base = ((size_t)(n * CCH) + o) * HW + l0 + 16 * w + 4 * g;
    float4 xr = *(const float4*)&x[base];
    float4 res;
    res.x = xr.x + acc[ct][0] + bias;
    res.y = xr.y + acc[ct][1] + bias;
    res.z = xr.z + acc[ct][2] + bias;
    res.w = xr.w + acc[ct][3] + bias;
    *(float4*)&out[base] = res;
  }
}

extern "C" void kernel_launch(void* const* d_in, const int* in_sizes, int n_in,
                              void* d_out, int out_size, void* d_ws, size_t ws_size,
                              hipStream_t stream){
  const float* x    = (const float*)d_in[0];
  const float* gnsc = (const float*)d_in[1];
  const float* gnb  = (const float*)d_in[2];
  const float* wq   = (const float*)d_in[3];
  const float* bq   = (const float*)d_in[4];
  const float* wk   = (const float*)d_in[5];
  const float* bk   = (const float*)d_in[6];
  const float* wv   = (const float*)d_in[7];
  const float* bv   = (const float*)d_in[8];
  const float* wp   = (const float*)d_in[9];
  const float* bp   = (const float*)d_in[10];
  float* out = (float*)d_out;

  char* ws = (char*)d_ws;
  const size_t BUF = (size_t)NB * HW * CCH * sizeof(unsigned short);  // 4 MiB
  float* stats       = (float*)ws;
  unsigned short* ht = (unsigned short*)(ws + 4096);
  unsigned short* Qg = (unsigned short*)(ws + 4096 + BUF);
  unsigned short* Kg = (unsigned short*)(ws + 4096 + 2 * BUF);
  unsigned short* Vt = (unsigned short*)(ws + 4096 + 3 * BUF);
  unsigned short* Op = (unsigned short*)(ws + 4096 + 4 * BUF);          // 2 splits, 8 MiB
  float*          Ml = (float*)(ws + 4096 + 6 * BUF);                   // 256 KiB
  unsigned short* Og = ht;  // ht dead after qkv_k; alias for combined attn output

  gn_stats_k<<<128, 256, 0, stream>>>(x, stats);
  gn_apply_k<<<dim3(64, NB), 256, 0, stream>>>(x, stats, gnsc, gnb, ht);
  qkv_k<<<dim3(64, NB), 256, 0, stream>>>(ht, wq, bq, wk, bk, wv, bv, Qg, Kg, Vt);
  attn_k<<<dim3(64, NB, SPLITS), 256, 0, stream>>>(Qg, Kg, Vt, Op, Ml);
  comb_k<<<1024, 256, 0, stream>>>(Op, Ml, Og);
  projout_k<<<dim3(64, NB), 256, 0, stream>>>(Og, wp, bp, x, out);
}

// Round 3
// 180.041 us; speedup vs baseline: 1.6285x; 1.5301x over previous
//
#include <hip/hip_runtime.h>

#define HW 4096
#define CCH 128
#define NB 4

typedef short bf16x8 __attribute__((ext_vector_type(8)));
typedef float f32x4 __attribute__((ext_vector_type(4)));

__device__ __forceinline__ unsigned short f2bf(float f){
  union { float fv; unsigned u; } v; v.fv = f;
  unsigned r = v.u + 0x7fffu + ((v.u >> 16) & 1u);
  return (unsigned short)(r >> 16);
}
__device__ __forceinline__ float bf2f(unsigned short u){
  return __uint_as_float(((unsigned)u) << 16);
}
__device__ __forceinline__ f32x4 mfma16(bf16x8 a, bf16x8 b, f32x4 c){
  return __builtin_amdgcn_mfma_f32_16x16x32_bf16(a, b, c, 0, 0, 0);
}
// async global->LDS, 16B per lane; LDS dest = wave-uniform base + lane*16
__device__ __forceinline__ void gll16(const void* g, void* l){
  __builtin_amdgcn_global_load_lds(
      (const __attribute__((address_space(1))) unsigned*)g,
      (__attribute__((address_space(3))) unsigned*)l, 16, 0, 0);
}

// ---------- Kernel A: group-norm stats ----------
__global__ __launch_bounds__(256) void gn_stats_k(const float* __restrict__ x,
                                                  float* __restrict__ stats){
  int gid = blockIdx.x;
  const float4* p = (const float4*)(x + (size_t)gid * 16384);
  float s = 0.f, q = 0.f;
  #pragma unroll
  for (int i = 0; i < 16; i++){
    float4 v = p[threadIdx.x + 256 * i];
    s += v.x + v.y + v.z + v.w;
    q += v.x * v.x + v.y * v.y + v.z * v.z + v.w * v.w;
  }
  #pragma unroll
  for (int d = 1; d < 64; d <<= 1){ s += __shfl_xor(s, d); q += __shfl_xor(q, d); }
  __shared__ float red[8];
  int w = threadIdx.x >> 6;
  if ((threadIdx.x & 63) == 0){ red[2 * w] = s; red[2 * w + 1] = q; }
  __syncthreads();
  if (threadIdx.x == 0){
    float S = red[0] + red[2] + red[4] + red[6];
    float Q = red[1] + red[3] + red[5] + red[7];
    float mean = S * (1.f / 16384.f);
    float var  = Q * (1.f / 16384.f) - mean * mean;
    stats[2 * gid]     = mean;
    stats[2 * gid + 1] = rsqrtf(var + 1e-5f);
  }
}

// ---------- Kernel B: apply GN + transpose NCHW -> [N, L, C] bf16 ----------
__global__ __launch_bounds__(256) void gn_apply_k(const float* __restrict__ x,
    const float* __restrict__ stats, const float* __restrict__ sc,
    const float* __restrict__ bi, unsigned short* __restrict__ ht){
  int n = blockIdx.y, l0 = blockIdx.x * 64, tid = threadIdx.x;
  __shared__ __align__(16) unsigned short hs[64][136];
  #pragma unroll
  for (int i = 0; i < 32; i++){
    int c = (tid >> 6) + 4 * i;
    int l = tid & 63;
    float v = x[((size_t)(n * CCH + c)) * HW + l0 + l];
    int grp = n * 32 + (c >> 2);
    float r = (v - stats[2 * grp]) * stats[2 * grp + 1] * sc[c] + bi[c];
    hs[l][c] = f2bf(r);
  }
  __syncthreads();
  #pragma unroll
  for (int i = 0; i < 4; i++){
    int ch = tid + 256 * i;
    int l = ch >> 4, cb = (ch & 15) * 8;
    *(uint4*)&ht[((size_t)(n * HW) + l0 + l) * CCH + cb] = *(const uint4*)&hs[l][cb];
  }
}

// ---------- Kernel C: fused QKV projection ----------
__global__ __launch_bounds__(256) void qkv_k(const unsigned short* __restrict__ ht,
    const float* __restrict__ wq, const float* __restrict__ bq,
    const float* __restrict__ wk, const float* __restrict__ bk,
    const float* __restrict__ wv, const float* __restrict__ bv,
    unsigned short* __restrict__ Qg, unsigned short* __restrict__ Kg,
    unsigned short* __restrict__ Vt){
  int n = blockIdx.y, l0 = blockIdx.x * 64, tid = threadIdx.x;
  int w = tid >> 6, lane = tid & 63, l15 = lane & 15, g = lane >> 4;
  __shared__ __align__(16) unsigned short hs[64][136];
  __shared__ __align__(16) unsigned short wm[128][136];
  {
    int row = tid >> 2, cq = (tid & 3) * 32;
    #pragma unroll
    for (int i = 0; i < 4; i++)
      *(uint4*)&hs[row][cq + 8 * i] =
          *(const uint4*)&ht[((size_t)(n * HW) + l0 + row) * CCH + cq + 8 * i];
  }
  const float* Wm[3] = {wq, wk, wv};
  const float* Bm[3] = {bq, bk, bv};
  #pragma unroll
  for (int m = 0; m < 3; m++){
    __syncthreads();
    #pragma unroll
    for (int i = 0; i < 16; i++){
      int ch = tid + 256 * i;
      int row = ch >> 5, c = (ch & 31) * 4;
      float4 v = *(const float4*)&Wm[m][row * CCH + c];
      ushort4 b; b.x = f2bf(v.x); b.y = f2bf(v.y); b.z = f2bf(v.z); b.w = f2bf(v.w);
      *(ushort4*)&wm[row][c] = b;
    }
    __syncthreads();
    bf16x8 a[4];
    #pragma unroll
    for (int kc = 0; kc < 4; kc++)
      a[kc] = *reinterpret_cast<const bf16x8*>(&hs[16 * w + l15][32 * kc + 8 * g]);
    f32x4 acc[8];
    #pragma unroll
    for (int ct = 0; ct < 8; ct++) acc[ct] = (f32x4)(0.f);
    #pragma unroll
    for (int ct = 0; ct < 8; ct++)
      #pragma unroll
      for (int kc = 0; kc < 4; kc++)
        acc[ct] = mfma16(a[kc],
            *reinterpret_cast<const bf16x8*>(&wm[16 * ct + l15][32 * kc + 8 * g]),
            acc[ct]);
    if (m < 2){
      float qs = (m == 0) ? 0.08838834764831845f : 1.0f;
      unsigned short* dst = (m == 0) ? Qg : Kg;
      #pragma unroll
      for (int ct = 0; ct < 8; ct++){
        int o = 16 * ct + l15;
        float bias = Bm[m][o];
        #pragma unroll
        for (int r = 0; r < 4; r++){
          int l = l0 + 16 * w + 4 * g + r;
          dst[((size_t)(n * HW) + l) * CCH + o] = f2bf((acc[ct][r] + bias) * qs);
        }
      }
    } else {
      #pragma unroll
      for (int ct = 0; ct < 8; ct++){
        int o = 16 * ct + l15;
        float bias = Bm[2][o];
        ushort4 pk;
        pk.x = f2bf(acc[ct][0] + bias); pk.y = f2bf(acc[ct][1] + bias);
        pk.z = f2bf(acc[ct][2] + bias); pk.w = f2bf(acc[ct][3] + bias);
        *(ushort4*)&Vt[((size_t)(n * CCH) + o) * HW + l0 + 16 * w + 4 * g] = pk;
      }
    }
  }
}

// ---------- Kernel D: flash attention, gll staging + swizzled LDS ----------
// LDS: Ks 16KB linear [64 rows x 256B, chunk swz c^(row&15)]
//      Vs 16KB linear [128 rows x 128B, chunk swz c^(row&7)]
//      Ps aliased into Ks region (per-wave 16x72 shorts @ w*2304B), extra barrier.
__global__ __launch_bounds__(256, 4) void attn_k(const unsigned short* __restrict__ Qg,
    const unsigned short* __restrict__ Kg, const unsigned short* __restrict__ Vt,
    unsigned short* __restrict__ Op, float* __restrict__ Ml, int kvs, int nt){
  int n = blockIdx.y, q0 = blockIdx.x * 64, sp = blockIdx.z, tid = threadIdx.x;
  int w = tid >> 6, lane = tid & 63, l15 = lane & 15, g = lane >> 4;
  __shared__ __align__(16) char lds[32768];
  char* Ks = lds;            // 16 KB; also hosts Ps
  char* Vs = lds + 16384;    // 16 KB

  bf16x8 qf[4];
  #pragma unroll
  for (int kc = 0; kc < 4; kc++)
    qf[kc] = *reinterpret_cast<const bf16x8*>(
        &Qg[((size_t)(n * HW) + q0 + 16 * w + l15) * CCH + 32 * kc + 8 * g]);
  f32x4 ov[8];
  #pragma unroll
  for (int i = 0; i < 8; i++) ov[i] = (f32x4)(0.f);
  float mrun[4] = {-3.0e38f, -3.0e38f, -3.0e38f, -3.0e38f};
  float lrun[4] = {0.f, 0.f, 0.f, 0.f};

  // per-lane swizzled global source pointers for the 4+4 gll ops of this wave
  const char* kp[4]; const char* vp[4];
  {
    const char* kbase = (const char*)Kg + ((size_t)(n * HW) + sp * kvs) * (CCH * 2);
    const char* vbase = (const char*)Vt + (size_t)(n * CCH) * (HW * 2) + (size_t)sp * kvs * 2;
    #pragma unroll
    for (int i = 0; i < 4; i++){
      int C = (w * 4 + i) * 64 + lane;          // K chunk id (16 chunks/row)
      int row = C >> 4, c16 = (C & 15) ^ (row & 15);
      kp[i] = kbase + row * 256 + c16 * 16;
      int Cv = (w * 4 + i) * 64 + lane;         // V chunk id (8 chunks/row)
      int vrow = Cv >> 3, c8 = (Cv & 7) ^ (vrow & 7);
      vp[i] = vbase + (size_t)vrow * (HW * 2) + c8 * 16;
    }
  }
  char* kl = Ks + w * 4096;   // 4 x 1KB LDS dest per wave
  char* vl = Vs + w * 4096;

  for (int t = 0; t < nt; t++){
    __syncthreads();                 // B1: prev PV done with Ps/Vs
    #pragma unroll
    for (int i = 0; i < 4; i++) gll16(kp[i] + t * 16384, kl + i * 1024);
    #pragma unroll
    for (int i = 0; i < 4; i++) gll16(vp[i] + t * 128,   vl + i * 1024);
    __syncthreads();                 // B2: vmcnt drain -> K/V tile visible

    // S = Q K^T  (Q pre-scaled by C^-0.5)
    f32x4 s[4];
    #pragma unroll
    for (int ct = 0; ct < 4; ct++){
      f32x4 acc = (f32x4)(0.f);
      #pragma unroll
      for (int kc = 0; kc < 4; kc++){
        int row = 16 * ct + l15;
        int c16 = (4 * kc + g) ^ (row & 15);
        bf16x8 kf = *(const bf16x8*)(Ks + row * 256 + c16 * 16);
        acc = mfma16(qf[kc], kf, acc);
      }
      s[ct] = acc;
    }
    // online softmax (16-lane group reduce)
    float mx[4];
    #pragma unroll
    for (int r = 0; r < 4; r++)
      mx[r] = fmaxf(fmaxf(s[0][r], s[1][r]), fmaxf(s[2][r], s[3][r]));
    #pragma unroll
    for (int d = 1; d < 16; d <<= 1)
      #pragma unroll
      for (int r = 0; r < 4; r++) mx[r] = fmaxf(mx[r], __shfl_xor(mx[r], d));
    float al[4];
    #pragma unroll
    for (int r = 0; r < 4; r++){
      float mn = fmaxf(mrun[r], mx[r]);
      al[r] = __expf(mrun[r] - mn);
      mrun[r] = mn;
    }
    #pragma unroll
    for (int ct = 0; ct < 4; ct++)
      #pragma unroll
      for (int r = 0; r < 4; r++) s[ct][r] = __expf(s[ct][r] - mrun[r]);
    float rs[4];
    #pragma unroll
    for (int r = 0; r < 4; r++) rs[r] = s[0][r] + s[1][r] + s[2][r] + s[3][r];
    #pragma unroll
    for (int d = 1; d < 16; d <<= 1)
      #pragma unroll
      for (int r = 0; r < 4; r++) rs[r] += __shfl_xor(rs[r], d);
    #pragma unroll
    for (int r = 0; r < 4; r++) lrun[r] = lrun[r] * al[r] + rs[r];
    #pragma unroll
    for (int ct = 0; ct < 8; ct++)
      #pragma unroll
      for (int r = 0; r < 4; r++) ov[ct][r] *= al[r];

    __syncthreads();                 // B3: all waves done reading Ks -> Ps may overwrite
    char* Pw = Ks + w * 2304;        // per-wave P: [16][72] shorts, 144B row stride
    #pragma unroll
    for (int ct = 0; ct < 4; ct++)
      #pragma unroll
      for (int r = 0; r < 4; r++)
        *(unsigned short*)(Pw + (4 * g + r) * 144 + (16 * ct + l15) * 2) = f2bf(s[ct][r]);
    // O~ += P V
    #pragma unroll
    for (int ct = 0; ct < 8; ct++){
      #pragma unroll
      for (int kc = 0; kc < 2; kc++){
        bf16x8 pa = *(const bf16x8*)(Pw + l15 * 144 + (32 * kc + 8 * g) * 2);
        int row = 16 * ct + l15;
        int c8 = (4 * kc + g) ^ (row & 7);
        bf16x8 vf = *(const bf16x8*)(Vs + row * 128 + c8 * 16);
        ov[ct] = mfma16(pa, vf, ov[ct]);
      }
    }
  }
  // epilogue: unnormalized O~ + (m, l)
  size_t obase = (size_t)((sp * NB + n) * HW);
  #pragma unroll
  for (int ct = 0; ct < 8; ct++){
    int o = 16 * ct + l15;
    #pragma unroll
    for (int r = 0; r < 4; r++){
      int l = q0 + 16 * w + 4 * g + r;
      Op[(obase + l) * CCH + o] = f2bf(ov[ct][r]);
    }
  }
  if (l15 == 0){
    #pragma unroll
    for (int r = 0; r < 4; r++){
      int l = q0 + 16 * w + 4 * g + r;
      Ml[(obase + l) * 2]     = mrun[r];
      Ml[(obase + l) * 2 + 1] = lrun[r];
    }
  }
}

// ---------- Kernel D2: combine the KV splits ----------
__global__ __launch_bounds__(256) void comb_k(const unsigned short* __restrict__ Op,
    const float* __restrict__ Ml, unsigned short* __restrict__ Og, int nsplit){
  int idx = blockIdx.x * 256 + threadIdx.x;
  int row = idx >> 4, cb = (idx & 15) * 8;
  const size_t SSTR = (size_t)NB * HW;
  float mv = -3.0e38f;
  for (int s = 0; s < nsplit; s++) mv = fmaxf(mv, Ml[(s * SSTR + row) * 2]);
  float wgt[4]; float denom = 0.f;
  for (int s = 0; s < nsplit; s++){
    float ms = Ml[(s * SSTR + row) * 2], ls = Ml[(s * SSTR + row) * 2 + 1];
    wgt[s] = __expf(ms - mv);
    denom += wgt[s] * ls;
  }
  float inv = 1.f / denom;
  float fa[8];
  #pragma unroll
  for (int j = 0; j < 8; j++) fa[j] = 0.f;
  for (int s = 0; s < nsplit; s++){
    uint4 a = *(const uint4*)&Op[(s * SSTR + row) * CCH + cb];
    const unsigned short* au = (const unsigned short*)&a;
    #pragma unroll
    for (int j = 0; j < 8; j++) fa[j] += wgt[s] * bf2f(au[j]);
  }
  ushort4 lo, hi;
  lo.x = f2bf(fa[0] * inv); lo.y = f2bf(fa[1] * inv);
  lo.z = f2bf(fa[2] * inv); lo.w = f2bf(fa[3] * inv);
  hi.x = f2bf(fa[4] * inv); hi.y = f2bf(fa[5] * inv);
  hi.z = f2bf(fa[6] * inv); hi.w = f2bf(fa[7] * inv);
  *(ushort4*)&Og[(size_t)row * CCH + cb] = lo;
  *(ushort4*)&Og[(size_t)row * CCH + cb + 4] = hi;
}

// ---------- Kernel E: output projection + bias + residual ----------
__global__ __launch_bounds__(256) void projout_k(const unsigned short* __restrict__ Og,
    const float* __restrict__ wp, const float* __restrict__ bp,
    const float* __restrict__ x, float* __restrict__ out){
  int n = blockIdx.y, l0 = blockIdx.x * 64, tid = threadIdx.x;
  int w = tid >> 6, lane = tid & 63, l15 = lane & 15, g = lane >> 4;
  __shared__ __align__(16) unsigned short hs[64][136];
  __shared__ __align__(16) unsigned short wm[128][136];
  {
    int row = tid >> 2, cq = (tid & 3) * 32;
    #pragma unroll
    for (int i = 0; i < 4; i++)
      *(uint4*)&hs[row][cq + 8 * i] =
          *(const uint4*)&Og[((size_t)(n * HW) + l0 + row) * CCH + cq + 8 * i];
  }
  #pragma unroll
  for (int i = 0; i < 16; i++){
    int ch = tid + 256 * i;
    int row = ch >> 5, c = (ch & 31) * 4;
    float4 v = *(const float4*)&wp[row * CCH + c];
    ushort4 b; b.x = f2bf(v.x); b.y = f2bf(v.y); b.z = f2bf(v.z); b.w = f2bf(v.w);
    *(ushort4*)&wm[row][c] = b;
  }
  __syncthreads();
  bf16x8 a[4];
  #pragma unroll
  for (int kc = 0; kc < 4; kc++)
    a[kc] = *reinterpret_cast<const bf16x8*>(&hs[16 * w + l15][32 * kc + 8 * g]);
  f32x4 acc[8];
  #pragma unroll
  for (int ct = 0; ct < 8; ct++) acc[ct] = (f32x4)(0.f);
  #pragma unroll
  for (int ct = 0; ct < 8; ct++)
    #pragma unroll
    for (int kc = 0; kc < 4; kc++)
      acc[ct] = mfma16(a[kc],
          *reinterpret_cast<const bf16x8*>(&wm[16 * ct + l15][32 * kc + 8 * g]),
          acc[ct]);
  #pragma unroll
  for (int ct = 0; ct < 8; ct++){
    int o = 16 * ct + l15;
    float bias = bp[o];
    size_t base = ((size_t)(n * CCH) + o) * HW + l0 + 16 * w + 4 * g;
    float4 xr = *(const float4*)&x[base];
    float4 res;
    res.x = xr.x + acc[ct][0] + bias;
    res.y = xr.y + acc[ct][1] + bias;
    res.z = xr.z + acc[ct][2] + bias;
    res.w = xr.w + acc[ct][3] + bias;
    *(float4*)&out[base] = res;
  }
}

extern "C" void kernel_launch(void* const* d_in, const int* in_sizes, int n_in,
                              void* d_out, int out_size, void* d_ws, size_t ws_size,
                              hipStream_t stream){
  const float* x    = (const float*)d_in[0];
  const float* gnsc = (const float*)d_in[1];
  const float* gnb  = (const float*)d_in[2];
  const float* wq   = (const float*)d_in[3];
  const float* bq   = (const float*)d_in[4];
  const float* wk   = (const float*)d_in[5];
  const float* bk   = (const float*)d_in[6];
  const float* wv   = (const float*)d_in[7];
  const float* bv   = (const float*)d_in[8];
  const float* wp   = (const float*)d_in[9];
  const float* bp   = (const float*)d_in[10];
  float* out = (float*)d_out;

  char* ws = (char*)d_ws;
  const size_t BUF = (size_t)NB * HW * CCH * sizeof(unsigned short);  // 4 MiB
  // ws_size permitting, use 4 KV-splits (preferred, 4 blocks/CU); else 2.
  const size_t NEED4 = 4096 + 4 * BUF + 4 * BUF + (size_t)4 * NB * HW * 2 * sizeof(float);
  const int splits = (ws_size >= NEED4) ? 4 : 2;
  const int kvs = HW / splits, nt = kvs / 64;

  float* stats       = (float*)ws;
  unsigned short* ht = (unsigned short*)(ws + 4096);
  unsigned short* Qg = (unsigned short*)(ws + 4096 + BUF);
  unsigned short* Kg = (unsigned short*)(ws + 4096 + 2 * BUF);
  unsigned short* Vt = (unsigned short*)(ws + 4096 + 3 * BUF);
  unsigned short* Op = (unsigned short*)(ws + 4096 + 4 * BUF);
  float*          Ml = (float*)(ws + 4096 + 4 * BUF + (size_t)splits * BUF);
  unsigned short* Og = ht;  // ht dead after qkv_k

  gn_stats_k<<<128, 256, 0, stream>>>(x, stats);
  gn_apply_k<<<dim3(64, NB), 256, 0, stream>>>(x, stats, gnsc, gnb, ht);
  qkv_k<<<dim3(64, NB), 256, 0, stream>>>(ht, wq, bq, wk, bk, wv, bv, Qg, Kg, Vt);
  attn_k<<<dim3(64, NB, splits), 256, 0, stream>>>(Qg, Kg, Vt, Op, Ml, kvs, nt);
  comb_k<<<1024, 256, 0, stream>>>(Op, Ml, Og, splits);
  projout_k<<<dim3(64, NB), 256, 0, stream>>>(Og, wp, bp, x, out);
}

// Round 4
// 172.633 us; speedup vs baseline: 1.6984x; 1.0429x over previous
//
#include <hip/hip_runtime.h>

#define HW 4096
#define CCH 128
#define NB 4

typedef short bf16x8 __attribute__((ext_vector_type(8)));
typedef float f32x4 __attribute__((ext_vector_type(4)));

__device__ __forceinline__ unsigned short f2bf(float f){
  union { float fv; unsigned u; } v; v.fv = f;
  unsigned r = v.u + 0x7fffu + ((v.u >> 16) & 1u);
  return (unsigned short)(r >> 16);
}
__device__ __forceinline__ float bf2f(unsigned short u){
  return __uint_as_float(((unsigned)u) << 16);
}
__device__ __forceinline__ f32x4 mfma16(bf16x8 a, bf16x8 b, f32x4 c){
  return __builtin_amdgcn_mfma_f32_16x16x32_bf16(a, b, c, 0, 0, 0);
}
// async global->LDS, 16B/lane; LDS dest = wave-uniform base + lane*16
__device__ __forceinline__ void gll16(const void* g, void* l){
  __builtin_amdgcn_global_load_lds(
      (const __attribute__((address_space(1))) unsigned*)g,
      (__attribute__((address_space(3))) unsigned*)l, 16, 0, 0);
}

// ---------- Kernel A: group-norm stats + weight fp32->bf16 prep ----------
__global__ __launch_bounds__(256) void gn_stats_k(const float* __restrict__ x,
    float* __restrict__ stats,
    const float* __restrict__ wq, const float* __restrict__ wk,
    const float* __restrict__ wv, const float* __restrict__ wp,
    unsigned short* __restrict__ wqb, unsigned short* __restrict__ wkb,
    unsigned short* __restrict__ wvb, unsigned short* __restrict__ wpb){
  int tid = threadIdx.x;
  // weight prep: 4 matrices x 16384 floats = 16384 float4s over 128 blocks
  if (tid < 128){
    int f4 = blockIdx.x * 128 + tid;
    int m = f4 >> 12, e = f4 & 4095;
    const float* s4 = (m == 0) ? wq : ((m == 1) ? wk : ((m == 2) ? wv : wp));
    unsigned short* d4 = (m == 0) ? wqb : ((m == 1) ? wkb : ((m == 2) ? wvb : wpb));
    float4 v = *(const float4*)(s4 + e * 4);
    ushort4 b; b.x = f2bf(v.x); b.y = f2bf(v.y); b.z = f2bf(v.z); b.w = f2bf(v.w);
    *(ushort4*)(d4 + e * 4) = b;
  }
  int gid = blockIdx.x;
  const float4* p = (const float4*)(x + (size_t)gid * 16384);
  float s = 0.f, q = 0.f;
  #pragma unroll
  for (int i = 0; i < 16; i++){
    float4 v = p[tid + 256 * i];
    s += v.x + v.y + v.z + v.w;
    q += v.x * v.x + v.y * v.y + v.z * v.z + v.w * v.w;
  }
  #pragma unroll
  for (int d = 1; d < 64; d <<= 1){ s += __shfl_xor(s, d); q += __shfl_xor(q, d); }
  __shared__ float red[8];
  int w = tid >> 6;
  if ((tid & 63) == 0){ red[2 * w] = s; red[2 * w + 1] = q; }
  __syncthreads();
  if (tid == 0){
    float S = red[0] + red[2] + red[4] + red[6];
    float Q = red[1] + red[3] + red[5] + red[7];
    float mean = S * (1.f / 16384.f);
    float var  = Q * (1.f / 16384.f) - mean * mean;
    stats[2 * gid]     = mean;
    stats[2 * gid + 1] = rsqrtf(var + 1e-5f);
  }
}

// ---------- Kernel B: apply GN + transpose NCHW -> [N, L, C] bf16 ----------
__global__ __launch_bounds__(256) void gn_apply_k(const float* __restrict__ x,
    const float* __restrict__ stats, const float* __restrict__ sc,
    const float* __restrict__ bi, unsigned short* __restrict__ ht){
  int n = blockIdx.y, l0 = blockIdx.x * 32, tid = threadIdx.x;
  __shared__ __align__(16) unsigned short hs[32][136];
  #pragma unroll
  for (int i = 0; i < 16; i++){
    int c = (tid >> 5) + 8 * i;
    int l = tid & 31;
    float v = x[((size_t)(n * CCH + c)) * HW + l0 + l];
    int grp = n * 32 + (c >> 2);
    float r = (v - stats[2 * grp]) * stats[2 * grp + 1] * sc[c] + bi[c];
    hs[l][c] = f2bf(r);
  }
  __syncthreads();
  #pragma unroll
  for (int i = 0; i < 2; i++){
    int ch = tid + 256 * i;
    int l = ch >> 4, cb = (ch & 15) * 8;
    *(uint4*)&ht[((size_t)(n * HW) + l0 + l) * CCH + cb] = *(const uint4*)&hs[l][cb];
  }
}

// ---------- Kernel C: QKV projection, one matmul per block ----------
// grid (64, NB, 3); LDS: ht tile 16KB (swz) + W 32KB (swz); 3 blocks/CU
__global__ __launch_bounds__(256, 3) void qkv_k(const unsigned short* __restrict__ ht,
    const unsigned short* __restrict__ wqb, const unsigned short* __restrict__ wkb,
    const unsigned short* __restrict__ wvb,
    const float* __restrict__ bq, const float* __restrict__ bk,
    const float* __restrict__ bv,
    unsigned short* __restrict__ Qg, unsigned short* __restrict__ Kg,
    unsigned short* __restrict__ Vt){
  int n = blockIdx.y, l0 = blockIdx.x * 64, m = blockIdx.z, tid = threadIdx.x;
  int w = tid >> 6, lane = tid & 63, l15 = lane & 15, g = lane >> 4;
  __shared__ __align__(16) char lds[49152];
  char* hA = lds;            // 16KB [64 rows x 256B], chunk swz c^(row&15)
  char* WB = lds + 16384;    // 32KB [128 rows x 256B], chunk swz c^(row&15)
  const unsigned short* wsrc = (m == 0) ? wqb : ((m == 1) ? wkb : wvb);
  const float* bsrc = (m == 0) ? bq : ((m == 1) ? bk : bv);
  {
    const char* hb = (const char*)ht + ((size_t)(n * HW) + l0) * (CCH * 2);
    #pragma unroll
    for (int i = 0; i < 4; i++){
      int T = (4 * w + i) * 64 + lane;
      int row = T >> 4, c16 = (T & 15) ^ (row & 15);
      gll16(hb + row * 256 + c16 * 16, hA + (4 * w + i) * 1024);
    }
    const char* wb2 = (const char*)wsrc;
    #pragma unroll
    for (int i = 0; i < 8; i++){
      int T = (8 * w + i) * 64 + lane;
      int row = T >> 4, c16 = (T & 15) ^ (row & 15);
      gll16(wb2 + row * 256 + c16 * 16, WB + (8 * w + i) * 1024);
    }
  }
  __syncthreads();
  bf16x8 a[4];
  #pragma unroll
  for (int kc = 0; kc < 4; kc++)
    a[kc] = *(const bf16x8*)(hA + (16 * w + l15) * 256 + ((4 * kc + g) ^ l15) * 16);
  f32x4 acc[8];
  #pragma unroll
  for (int ct = 0; ct < 8; ct++) acc[ct] = (f32x4)(0.f);
  #pragma unroll
  for (int ct = 0; ct < 8; ct++)
    #pragma unroll
    for (int kc = 0; kc < 4; kc++){
      bf16x8 bfr = *(const bf16x8*)(WB + (16 * ct + l15) * 256 + ((4 * kc + g) ^ l15) * 16);
      acc[ct] = mfma16(a[kc], bfr, acc[ct]);
    }
  __syncthreads();   // all waves done reading WB; reuse as output-stage LDS
  if (m < 2){
    float qs = (m == 0) ? 0.08838834764831845f : 1.0f;
    unsigned short* dst = (m == 0) ? Qg : Kg;
    unsigned short* os = (unsigned short*)(lds + 16384);  // [64][136]
    #pragma unroll
    for (int ct = 0; ct < 8; ct++){
      int o = 16 * ct + l15;
      float bias = bsrc[o];
      #pragma unroll
      for (int r = 0; r < 4; r++)
        os[(16 * w + 4 * g + r) * 136 + o] = f2bf((acc[ct][r] + bias) * qs);
    }
    __syncthreads();
    #pragma unroll
    for (int i = 0; i < 4; i++){
      int T = tid + 256 * i;
      int row = T >> 4, cb = T & 15;
      *(uint4*)&dst[((size_t)(n * HW) + l0 + row) * CCH + cb * 8] =
          *(const uint4*)&os[row * 136 + cb * 8];
    }
  } else {
    unsigned short* os = (unsigned short*)(lds + 16384);  // [128][72]
    #pragma unroll
    for (int ct = 0; ct < 8; ct++){
      int o = 16 * ct + l15;
      float bias = bsrc[o];
      #pragma unroll
      for (int r = 0; r < 4; r++)
        os[o * 72 + 16 * w + 4 * g + r] = f2bf(acc[ct][r] + bias);
    }
    __syncthreads();
    #pragma unroll
    for (int i = 0; i < 4; i++){
      int T = tid + 256 * i;
      int row = T >> 3, c = T & 7;
      *(uint4*)&Vt[((size_t)(n * CCH) + row) * HW + l0 + c * 8] =
          *(const uint4*)&os[row * 72 + c * 8];
    }
  }
}

// ---------- Kernel D: flash attention, XCD-swizzled, defer-rescale ----------
__global__ __launch_bounds__(256, 4) void attn_k(const unsigned short* __restrict__ Qg,
    const unsigned short* __restrict__ Kg, const unsigned short* __restrict__ Vt,
    unsigned short* __restrict__ Op, float* __restrict__ Ml, int lsp){
  // chunked bijective XCD swizzle; decode order (q fastest, sp, n) so each
  // XCD's resident blocks share one n and a 2MB K/V/Q slice (L2-resident)
  int nbk = gridDim.x, cpx = nbk >> 3, b = blockIdx.x;
  int swz = (b & 7) * cpx + (b >> 3);
  int q0 = (swz & 63) * 64;
  int rest = swz >> 6;
  int splits = 1 << lsp;
  int sp = rest & (splits - 1);
  int n = rest >> lsp;
  int kvs = HW >> lsp, nt = 64 >> lsp;
  int tid = threadIdx.x;
  int w = tid >> 6, lane = tid & 63, l15 = lane & 15, g = lane >> 4;
  __shared__ __align__(16) char lds[32768];
  char* Ks = lds;            // 16 KB; also hosts Ps
  char* Vs = lds + 16384;    // 16 KB

  bf16x8 qf[4];
  #pragma unroll
  for (int kc = 0; kc < 4; kc++)
    qf[kc] = *reinterpret_cast<const bf16x8*>(
        &Qg[((size_t)(n * HW) + q0 + 16 * w + l15) * CCH + 32 * kc + 8 * g]);
  f32x4 ov[8];
  #pragma unroll
  for (int i = 0; i < 8; i++) ov[i] = (f32x4)(0.f);
  float mrun[4] = {-3.0e38f, -3.0e38f, -3.0e38f, -3.0e38f};
  float lrun[4] = {0.f, 0.f, 0.f, 0.f};

  const char* kp[4]; const char* vp[4];
  {
    const char* kbase = (const char*)Kg + ((size_t)(n * HW) + sp * kvs) * (CCH * 2);
    const char* vbase = (const char*)Vt + (size_t)(n * CCH) * (HW * 2) + (size_t)sp * kvs * 2;
    #pragma unroll
    for (int i = 0; i < 4; i++){
      int C = (w * 4 + i) * 64 + lane;
      int row = C >> 4, c16 = (C & 15) ^ (row & 15);
      kp[i] = kbase + row * 256 + c16 * 16;
      int vrow = C >> 3, c8 = (C & 7) ^ (vrow & 7);
      vp[i] = vbase + (size_t)vrow * (HW * 2) + c8 * 16;
    }
  }
  char* kl = Ks + w * 4096;
  char* vl = Vs + w * 4096;

  for (int t = 0; t < nt; t++){
    __syncthreads();                 // B1: prev PV done with Ps/Vs
    #pragma unroll
    for (int i = 0; i < 4; i++) gll16(kp[i] + t * 16384, kl + i * 1024);
    #pragma unroll
    for (int i = 0; i < 4; i++) gll16(vp[i] + t * 128,   vl + i * 1024);
    __syncthreads();                 // B2: K/V tile visible

    f32x4 s[4];
    __builtin_amdgcn_s_setprio(1);
    #pragma unroll
    for (int ct = 0; ct < 4; ct++){
      f32x4 acc = (f32x4)(0.f);
      #pragma unroll
      for (int kc = 0; kc < 4; kc++){
        bf16x8 kf = *(const bf16x8*)(Ks + (16 * ct + l15) * 256 + ((4 * kc + g) ^ l15) * 16);
        acc = mfma16(qf[kc], kf, acc);
      }
      s[ct] = acc;
    }
    __builtin_amdgcn_s_setprio(0);
    // online softmax with defer-rescale (THR=8)
    float mx[4];
    #pragma unroll
    for (int r = 0; r < 4; r++)
      mx[r] = fmaxf(fmaxf(s[0][r], s[1][r]), fmaxf(s[2][r], s[3][r]));
    #pragma unroll
    for (int d = 1; d < 16; d <<= 1)
      #pragma unroll
      for (int r = 0; r < 4; r++) mx[r] = fmaxf(mx[r], __shfl_xor(mx[r], d));
    int need = 0;
    #pragma unroll
    for (int r = 0; r < 4; r++) need |= (mx[r] > mrun[r] + 8.0f) ? 1 : 0;
    if (__any(need)){
      float al[4];
      #pragma unroll
      for (int r = 0; r < 4; r++){
        float mn = fmaxf(mrun[r], mx[r]);
        al[r] = __expf(mrun[r] - mn);
        mrun[r] = mn;
        lrun[r] *= al[r];
      }
      #pragma unroll
      for (int ct = 0; ct < 8; ct++)
        #pragma unroll
        for (int r = 0; r < 4; r++) ov[ct][r] *= al[r];
    }
    #pragma unroll
    for (int ct = 0; ct < 4; ct++)
      #pragma unroll
      for (int r = 0; r < 4; r++) s[ct][r] = __expf(s[ct][r] - mrun[r]);
    float rs[4];
    #pragma unroll
    for (int r = 0; r < 4; r++) rs[r] = s[0][r] + s[1][r] + s[2][r] + s[3][r];
    #pragma unroll
    for (int d = 1; d < 16; d <<= 1)
      #pragma unroll
      for (int r = 0; r < 4; r++) rs[r] += __shfl_xor(rs[r], d);
    #pragma unroll
    for (int r = 0; r < 4; r++) lrun[r] += rs[r];

    __syncthreads();                 // B3: Ks reads done -> Ps may overwrite
    char* Pw = Ks + w * 2304;        // per-wave P [16][72] shorts
    #pragma unroll
    for (int ct = 0; ct < 4; ct++)
      #pragma unroll
      for (int r = 0; r < 4; r++)
        *(unsigned short*)(Pw + (4 * g + r) * 144 + (16 * ct + l15) * 2) = f2bf(s[ct][r]);
    __builtin_amdgcn_s_setprio(1);
    #pragma unroll
    for (int ct = 0; ct < 8; ct++){
      #pragma unroll
      for (int kc = 0; kc < 2; kc++){
        bf16x8 pa = *(const bf16x8*)(Pw + l15 * 144 + (32 * kc + 8 * g) * 2);
        bf16x8 vf = *(const bf16x8*)(Vs + (16 * ct + l15) * 128 + ((4 * kc + g) ^ (l15 & 7)) * 16);
        ov[ct] = mfma16(pa, vf, ov[ct]);
      }
    }
    __builtin_amdgcn_s_setprio(0);
  }
  size_t obase = (size_t)((sp * NB + n) * HW);
  #pragma unroll
  for (int ct = 0; ct < 8; ct++){
    int o = 16 * ct + l15;
    #pragma unroll
    for (int r = 0; r < 4; r++){
      int l = q0 + 16 * w + 4 * g + r;
      Op[(obase + l) * CCH + o] = f2bf(ov[ct][r]);
    }
  }
  if (l15 == 0){
    #pragma unroll
    for (int r = 0; r < 4; r++){
      int l = q0 + 16 * w + 4 * g + r;
      Ml[(obase + l) * 2]     = mrun[r];
      Ml[(obase + l) * 2 + 1] = lrun[r];
    }
  }
}

// ---------- Kernel E: combine splits + output projection + residual ----------
// grid (128, NB), 32 rows/block; LDS: hs 8.7KB (pad) + wp 32KB (swz)
__global__ __launch_bounds__(256) void projout_k(const unsigned short* __restrict__ Op,
    const float* __restrict__ Ml, const unsigned short* __restrict__ wpb,
    const float* __restrict__ bp, const float* __restrict__ x,
    float* __restrict__ out, int splits){
  int n = blockIdx.y, l0 = blockIdx.x * 32, tid = threadIdx.x;
  int w = tid >> 6, lane = tid & 63, l15 = lane & 15, g = lane >> 4;
  __shared__ __align__(16) unsigned short hs[32][136];
  __shared__ __align__(16) char WB[32768];
  {
    const char* wb2 = (const char*)wpb;
    #pragma unroll
    for (int i = 0; i < 8; i++){
      int T = (8 * w + i) * 64 + lane;
      int row = T >> 4, c16 = (T & 15) ^ (row & 15);
      gll16(wb2 + row * 256 + c16 * 16, WB + (8 * w + i) * 1024);
    }
  }
  const size_t SSTR = (size_t)NB * HW;
  #pragma unroll
  for (int i = 0; i < 2; i++){
    int T = tid + 256 * i;
    int row = T >> 4, cb = (T & 15) * 8;
    size_t gl = (size_t)n * HW + l0 + row;
    float mv = -3.0e38f;
    #pragma unroll
    for (int s = 0; s < 4; s++)
      if (s < splits) mv = fmaxf(mv, Ml[(s * SSTR + gl) * 2]);
    float fa[8];
    #pragma unroll
    for (int j = 0; j < 8; j++) fa[j] = 0.f;
    float denom = 0.f;
    #pragma unroll
    for (int s = 0; s < 4; s++){
      if (s < splits){
        float wgt = __expf(Ml[(s * SSTR + gl) * 2] - mv);
        denom += wgt * Ml[(s * SSTR + gl) * 2 + 1];
        uint4 a = *(const uint4*)&Op[(s * SSTR + gl) * CCH + cb];
        const unsigned short* au = (const unsigned short*)&a;
        #pragma unroll
        for (int j = 0; j < 8; j++) fa[j] += wgt * bf2f(au[j]);
      }
    }
    float inv = 1.f / denom;
    #pragma unroll
    for (int j = 0; j < 8; j++) hs[row][cb + j] = f2bf(fa[j] * inv);
  }
  __syncthreads();
  int rt = w & 1, cg = w >> 1;
  bf16x8 a[4];
  #pragma unroll
  for (int kc = 0; kc < 4; kc++)
    a[kc] = *reinterpret_cast<const bf16x8*>(&hs[16 * rt + l15][32 * kc + 8 * g]);
  f32x4 acc[4];
  #pragma unroll
  for (int ci = 0; ci < 4; ci++) acc[ci] = (f32x4)(0.f);
  #pragma unroll
  for (int ci = 0; ci < 4; ci++){
    int o = 16 * (cg * 4 + ci) + l15;
    #pragma unroll
    for (int kc = 0; kc < 4; kc++){
      bf16x8 bfr = *(const bf16x8*)(WB + o * 256 + ((4 * kc + g) ^ l15) * 16);
      acc[ci] = mfma16(a[kc], bfr, acc[ci]);
    }
  }
  #pragma unroll
  for (int ci = 0; ci < 4; ci++){
    int o = 16 * (cg * 4 + ci) + l15;
    float bias = bp[o];
    size_t base = ((size_t)(n * CCH) + o) * HW + l0 + 16 * rt + 4 * g;
    float4 xr = *(const float4*)&x[base];
    float4 res;
    res.x = xr.x + acc[ci][0] + bias;
    res.y = xr.y + acc[ci][1] + bias;
    res.z = xr.z + acc[ci][2] + bias;
    res.w = xr.w + acc[ci][3] + bias;
    *(float4*)&out[base] = res;
  }
}

extern "C" void kernel_launch(void* const* d_in, const int* in_sizes, int n_in,
                              void* d_out, int out_size, void* d_ws, size_t ws_size,
                              hipStream_t stream){
  const float* x    = (const float*)d_in[0];
  const float* gnsc = (const float*)d_in[1];
  const float* gnb  = (const float*)d_in[2];
  const float* wq   = (const float*)d_in[3];
  const float* bq   = (const float*)d_in[4];
  const float* wk   = (const float*)d_in[5];
  const float* bk   = (const float*)d_in[6];
  const float* wv   = (const float*)d_in[7];
  const float* bv   = (const float*)d_in[8];
  const float* wp   = (const float*)d_in[9];
  const float* bp   = (const float*)d_in[10];
  float* out = (float*)d_out;

  char* ws = (char*)d_ws;
  const size_t BUF = (size_t)NB * HW * CCH * sizeof(unsigned short);  // 4 MiB
  const size_t WOFF = 4096;                  // stats 4KB
  const size_t HTOFF = WOFF + 4 * 32768;     // 4 bf16 weight mats (128KB)
  const size_t NEED4 = HTOFF + 8 * BUF + (size_t)4 * NB * HW * 2 * sizeof(float);
  const int lsp = (ws_size >= NEED4) ? 2 : 1;
  const int splits = 1 << lsp;

  float* stats        = (float*)ws;
  unsigned short* wqb = (unsigned short*)(ws + WOFF);
  unsigned short* wkb = (unsigned short*)(ws + WOFF + 32768);
  unsigned short* wvb = (unsigned short*)(ws + WOFF + 65536);
  unsigned short* wpb = (unsigned short*)(ws + WOFF + 98304);
  unsigned short* ht  = (unsigned short*)(ws + HTOFF);
  unsigned short* Qg  = (unsigned short*)(ws + HTOFF + BUF);
  unsigned short* Kg  = (unsigned short*)(ws + HTOFF + 2 * BUF);
  unsigned short* Vt  = (unsigned short*)(ws + HTOFF + 3 * BUF);
  unsigned short* Op  = (unsigned short*)(ws + HTOFF + 4 * BUF);
  float*          Ml  = (float*)(ws + HTOFF + 4 * BUF + (size_t)splits * BUF);

  gn_stats_k<<<128, 256, 0, stream>>>(x, stats, wq, wk, wv, wp, wqb, wkb, wvb, wpb);
  gn_apply_k<<<dim3(128, NB), 256, 0, stream>>>(x, stats, gnsc, gnb, ht);
  qkv_k<<<dim3(64, NB, 3), 256, 0, stream>>>(ht, wqb, wkb, wvb, bq, bk, bv, Qg, Kg, Vt);
  attn_k<<<dim3(64 * NB * splits), 256, 0, stream>>>(Qg, Kg, Vt, Op, Ml, lsp);
  projout_k<<<dim3(128, NB), 256, 0, stream>>>(Op, Ml, wpb, bp, x, out, splits);
}